// Round 6
// baseline (566.446 us; speedup 1.0000x reference)
//
#include <hip/hip_runtime.h>
#include <hip/hip_bf16.h>

// Linear: C[M,N] = A[M,K] @ W[N,K]^T + bias[N]. fp32 in/out (harness maps fp16
// reference -> fp32 buffers), bf16 MFMA compute (2% threshold).
//
// Round 13: occupancy dominates schedule. r0 (128^2, ~3 blocks/CU, full
// drain) = 242 us @ 53-55% MfmaUtil beat BOTH careful 1-block/CU 256^2
// schedules (r4 267 us/45%, r5 250 us/48.5%): inter-block wave overlap
// (m114) fills the MFMA pipe during ds_read/barrier windows better than any
// intra-block pipeline at 8 lockstep waves. This round combines the two
// proven ingredients:
//   * 128x128 tile, 4 waves, verified fragment/epilogue math (r0) ->
//     VGPR ~120 unified, 3 blocks/CU.
//   * ring-3 x 16 KiB slots (slot = one 32-k K-step: A 128x32 + B 128x32)
//     = 48 KiB LDS -> still 3 blocks/CU. stage(j+2) issued during step j
//     (~1.5 steps = ~900 cyc cover); per-step wait vmcnt(4) (newest stage
//     stays in flight), vmcnt(0) only at the last step; ONE raw s_barrier
//     per step. Counted pipeline + multi-block overlap simultaneously.
//   * pack kernel: r5 verbatim (128-row x 32-k blocks, 2-bit XOR swizzle
//     cp = c ^ ((row>>1)&3); 2 lanes/bank on ds_read = free, measured 0
//     conflicts).
// Clean A/B vs r0: same tile/occupancy, drain -> counted ring is the only
// schedule variable. Predicted: gemm 190-215 us @ 60-68% MfmaUtil; null
// (~240 us @ ~55%) => structure ceiling, pivot to 32x32x16 MFMA shape.

typedef unsigned short u16;
typedef unsigned int u32;
typedef __bf16 bf16x8 __attribute__((ext_vector_type(8)));
typedef float f32x4 __attribute__((ext_vector_type(4)));
typedef u32 u32x4 __attribute__((ext_vector_type(4)));

#define M_DIM 8192
#define N_DIM 4096
#define K_DIM 4096

#define NT 128                          // 32-k K-steps
#define BLK_ELEMS 4096                  // 128 rows x 32 k per packed block
#define SLOT_ELEMS 8192                 // ring slot: A block + B block

#define A_CHUNKS ((M_DIM / 128) * NT * 128 * 4)   // 4,194,304 16B chunks
#define W_CHUNKS ((N_DIM / 128) * NT * 128 * 4)   // 2,097,152
#define A_PACK_BYTES ((size_t)A_CHUNKS * 16)      // 64 MiB
#define W_PACK_BYTES ((size_t)W_CHUNKS * 16)      // 32 MiB

// pack two fp32 -> (bf16(hi)<<16)|bf16(lo) by byte-perm truncation
__device__ __forceinline__ u32 pack2bf(float lo, float hi) {
    return __builtin_amdgcn_perm(__float_as_uint(hi), __float_as_uint(lo),
                                 0x07060302u);
}

__device__ __forceinline__ void g2l16(const u16* g, __bf16* l) {
    __builtin_amdgcn_global_load_lds((__attribute__((address_space(1))) void*)g,
                                     (__attribute__((address_space(3))) void*)l,
                                     16, 0, 0);
}

// ---------------- Phase 1: convert + block-pack + swizzle (r5 verbatim) -----
// Packed layout: [panel][kstep][row][cp], 16B chunk cp at row r holds source
// chunk c = cp ^ ((r>>1)&3). One thread per chunk. A wave covers 16 rows x 4
// chunks: per row the 4 chunks are a permutation of one contiguous 128 B
// source segment (coalesced); writes fully linear (1 KiB/wave).
__global__ __launch_bounds__(256) void pack_bf16_kernel(
    const float* __restrict__ A, const float* __restrict__ W,
    u32x4* __restrict__ aP, u32x4* __restrict__ wP)
{
    int gid = blockIdx.x * 256 + threadIdx.x;
    const float* src;
    u32x4* dst;
    int id;
    if (gid < A_CHUNKS) { src = A; dst = aP; id = gid; }
    else                { src = W; dst = wP; id = gid - A_CHUNKS; }

    const int cp  = id & 3;
    const int row = (id >> 2) & 127;
    const int j   = (id >> 9) & 127;          // k-step
    const int mp  = id >> 16;                 // 128-row panel
    const int c   = cp ^ ((row >> 1) & 3);    // source chunk

    const float* p = src + (size_t)(mp * 128 + row) * K_DIM + j * 32 + c * 8;
    f32x4 v0 = __builtin_nontemporal_load((const f32x4*)(p));
    f32x4 v1 = __builtin_nontemporal_load((const f32x4*)(p + 4));
    dst[id] = u32x4{pack2bf(v0[0], v0[1]), pack2bf(v0[2], v0[3]),
                    pack2bf(v1[0], v1[1]), pack2bf(v1[2], v1[3])};
}

// ---------------- Phase 2: 128x128 ring-3 counted-vmcnt GEMM ---------------
// 256 thr / 4 waves (2M x 2N, wave tile 64x64). Ring slot holds one 32-k
// K-step (A panel block + W panel block, 8 KB each). Steady state: stage(j+2)
// issued during step j; wait vmcnt(4) keeps the newest stage in flight.
// 4 g2l16 per thread per stage.
__global__ __launch_bounds__(256, 3) void gemm128_ring3_kernel(
    const u16* __restrict__ aP,      // packed A blocks (128x32, swizzled)
    const u16* __restrict__ wP,      // packed W blocks (128x32, swizzled)
    const float* __restrict__ bias,  // [N] fp32
    float* __restrict__ C)           // [M, N] fp32
{
    __shared__ __attribute__((aligned(16))) __bf16 ring[3][SLOT_ELEMS];

    const int tid  = threadIdx.x;
    const int lane = tid & 63;
    const int wave = tid >> 6;        // 0..3
    const int quad = lane >> 4;
    const int l16  = lane & 15;
    const int wm   = wave >> 1;       // 0..1 (M half)
    const int wn   = wave & 1;        // 0..1 (N half)

    // XCD-bijective swizzle: 2048 blocks, 256/XCD contiguous (8 bm x 32 bn).
    const int bid = blockIdx.x;
    const int swz = (bid & 7) * 256 + (bid >> 3);
    const int bm  = swz >> 5;         // 0..63
    const int bn  = swz & 31;         // 0..31

    const u16* aB = aP + (size_t)bm * NT * BLK_ELEMS + tid * 8;
    const u16* wB = wP + (size_t)bn * NT * BLK_ELEMS + tid * 8;

    auto stage = [&](int t, int sl) {
        __bf16* s = &ring[sl][tid * 8];
        const size_t o = (size_t)t * BLK_ELEMS;
        g2l16(aB + o,        s);
        g2l16(aB + o + 2048, s + 2048);
        g2l16(wB + o,        s + 4096);
        g2l16(wB + o + 2048, s + 6144);
    };

    f32x4 acc[4][4];
#pragma unroll
    for (int i = 0; i < 4; ++i)
#pragma unroll
        for (int j = 0; j < 4; ++j)
            acc[i][j] = f32x4{0.f, 0.f, 0.f, 0.f};

    // read offsets (elems in slot): row = (wm|wn)*64 + mi*16 + l16; the
    // swizzle bits (row>>1)&3 == (l16>>1)&3 since 16|64-multiples keep
    // bits 1-2 of row/2 unchanged mod 4 only via l16.
    const int cpq  = (quad ^ ((l16 >> 1) & 3)) * 8;
    const int aOff = (wm * 64 + l16) * 32 + cpq;          // + mi*512
    const int bOff = 4096 + (wn * 64 + l16) * 32 + cpq;   // + ni*512

    stage(0, 0);
    stage(1, 1);

    int sr = 0;       // slot of step j
    int sw = 2;       // slot of step j+2
    for (int j = 0; j < NT; ++j) {
        // counted wait: stages j and j+1 in flight (8 ops); keep newest 4.
        if (j + 1 < NT) asm volatile("s_waitcnt vmcnt(4)" ::: "memory");
        else            asm volatile("s_waitcnt vmcnt(0)" ::: "memory");
        __builtin_amdgcn_s_barrier();
        asm volatile("" ::: "memory");   // pin stage/ds_read after barrier

        if (j + 2 < NT) stage(j + 2, sw);   // overwrites slot of step j-1

        const __bf16* L = &ring[sr][0];
        bf16x8 af[4], bfr[4];
#pragma unroll
        for (int mi = 0; mi < 4; ++mi)
            af[mi] = *(const bf16x8*)&L[aOff + mi * 512];
#pragma unroll
        for (int ni = 0; ni < 4; ++ni)
            bfr[ni] = *(const bf16x8*)&L[bOff + ni * 512];

        __builtin_amdgcn_s_setprio(1);
#pragma unroll
        for (int mi = 0; mi < 4; ++mi)
#pragma unroll
            for (int ni = 0; ni < 4; ++ni)
                acc[mi][ni] = __builtin_amdgcn_mfma_f32_16x16x32_bf16(
                    af[mi], bfr[ni], acc[mi][ni], 0, 0, 0);
        __builtin_amdgcn_s_setprio(0);

        sr = (sr == 2) ? 0 : sr + 1;
        sw = (sw == 2) ? 0 : sw + 1;
    }

    // epilogue: C/D layout col = lane&15, row = quad*4 + reg; fp32 out + bias
    const int colBase = bn * 128 + wn * 64 + l16;
    const int rowBase = bm * 128 + wm * 64 + quad * 4;
#pragma unroll
    for (int ni = 0; ni < 4; ++ni) {
        const int col = colBase + ni * 16;
        const float bv = bias[col];
#pragma unroll
        for (int mi = 0; mi < 4; ++mi) {
            const int row = rowBase + mi * 16;
#pragma unroll
            for (int r = 0; r < 4; ++r)
                C[(size_t)(row + r) * N_DIM + col] = acc[mi][ni][r] + bv;
        }
    }
}

// ---------------- Fallback (round-3 kernel, ws too small) ----------------
__global__ __launch_bounds__(256, 2) void linear_f32_bf16mfma_kernel(
    const float* __restrict__ A, const float* __restrict__ W,
    const float* __restrict__ bias, float* __restrict__ C)
{
    __shared__ __attribute__((aligned(16))) __bf16 sA[128 * 64];
    __shared__ __attribute__((aligned(16))) __bf16 sB[128 * 64];

    const int tid  = threadIdx.x;
    const int lane = tid & 63;
    const int wave = tid >> 6;
    const int quad = lane >> 4;
    const int l16  = lane & 15;
    const int wm   = wave >> 1;
    const int wn   = wave & 1;
    const int bn = blockIdx.x;
    const int bm = blockIdx.y;
    const int srow = tid >> 3;
    const int scol = (tid & 7) * 8;

    const float* aBase = A + (size_t)(bm * 128 + srow) * K_DIM + scol;
    const float* bBase = W + (size_t)(bn * 128 + srow) * K_DIM + scol;

    f32x4 acc[4][4];
#pragma unroll
    for (int i = 0; i < 4; ++i)
#pragma unroll
        for (int j = 0; j < 4; ++j)
            acc[i][j] = f32x4{0.f, 0.f, 0.f, 0.f};

    const int aRow = wm * 64 + l16;
    const int bRow = wn * 64 + l16;
    const int kOff = quad * 8;

    for (int k0 = 0; k0 < K_DIM; k0 += 64) {
        f32x4 ga[4][2], gb[4][2];
#pragma unroll
        for (int it = 0; it < 4; ++it) {
            const float* pa = aBase + (size_t)(it * 32) * K_DIM + k0;
            const float* pb = bBase + (size_t)(it * 32) * K_DIM + k0;
            ga[it][0] = *(const f32x4*)(pa);
            ga[it][1] = *(const f32x4*)(pa + 4);
            gb[it][0] = *(const f32x4*)(pb);
            gb[it][1] = *(const f32x4*)(pb + 4);
        }
        u32x4 wa[4], wb[4];
#pragma unroll
        for (int it = 0; it < 4; ++it) {
            wa[it] = u32x4{pack2bf(ga[it][0][0], ga[it][0][1]),
                           pack2bf(ga[it][0][2], ga[it][0][3]),
                           pack2bf(ga[it][1][0], ga[it][1][1]),
                           pack2bf(ga[it][1][2], ga[it][1][3])};
            wb[it] = u32x4{pack2bf(gb[it][0][0], gb[it][0][1]),
                           pack2bf(gb[it][0][2], gb[it][0][3]),
                           pack2bf(gb[it][1][0], gb[it][1][1]),
                           pack2bf(gb[it][1][2], gb[it][1][3])};
        }
        __syncthreads();
#pragma unroll
        for (int it = 0; it < 4; ++it) {
            *(u32x4*)&sA[tid * 8 + it * 2048] = wa[it];
            *(u32x4*)&sB[tid * 8 + it * 2048] = wb[it];
        }
        __syncthreads();
#pragma unroll
        for (int ks = 0; ks < 64; ks += 32) {
            bf16x8 af[4], bfr[4];
#pragma unroll
            for (int mi = 0; mi < 4; ++mi)
                af[mi] = *(const bf16x8*)&sA[(aRow + mi * 16) * 64 + ks + kOff];
#pragma unroll
            for (int ni = 0; ni < 4; ++ni)
                bfr[ni] = *(const bf16x8*)&sB[(bRow + ni * 16) * 64 + ks + kOff];
#pragma unroll
            for (int mi = 0; mi < 4; ++mi)
#pragma unroll
                for (int ni = 0; ni < 4; ++ni)
                    acc[mi][ni] = __builtin_amdgcn_mfma_f32_16x16x32_bf16(
                        af[mi], bfr[ni], acc[mi][ni], 0, 0, 0);
        }
    }
    const int colBase = bn * 128 + wn * 64 + l16;
    const int rowBase = bm * 128 + wm * 64 + quad * 4;
#pragma unroll
    for (int ni = 0; ni < 4; ++ni) {
        const int col = colBase + ni * 16;
        const float bv = bias[col];
#pragma unroll
        for (int mi = 0; mi < 4; ++mi) {
            const int row = rowBase + mi * 16;
#pragma unroll
            for (int r = 0; r < 4; ++r)
                C[(size_t)(row + r) * N_DIM + col] = acc[mi][ni][r] + bv;
        }
    }
}

extern "C" void kernel_launch(void* const* d_in, const int* in_sizes, int n_in,
                              void* d_out, int out_size, void* d_ws, size_t ws_size,
                              hipStream_t stream) {
    const float* x = (const float*)d_in[0];   // [8192, 4096]
    const float* w = (const float*)d_in[1];   // [4096, 4096]
    const float* b = (const float*)d_in[2];   // [4096]
    float* out = (float*)d_out;

    if (ws_size >= A_PACK_BYTES + W_PACK_BYTES) {
        u32x4* aP = (u32x4*)d_ws;
        u32x4* wP = (u32x4*)((char*)d_ws + A_PACK_BYTES);
        const int total_chunks = A_CHUNKS + W_CHUNKS;
        pack_bf16_kernel<<<total_chunks / 256, 256, 0, stream>>>(x, w, aP, wP);
        gemm128_ring3_kernel<<<dim3(2048), 256, 0, stream>>>(
            (const u16*)aP, (const u16*)wP, b, out);
    } else {
        dim3 grid(N_DIM / 128, M_DIM / 128);
        linear_f32_bf16mfma_kernel<<<grid, 256, 0, stream>>>(x, w, b, out);
    }
}

// Round 7
// 467.870 us; speedup vs baseline: 1.2107x; 1.2107x over previous
//
#include <hip/hip_runtime.h>
#include <hip/hip_bf16.h>

// Linear: C[M,N] = A[M,K] @ W[N,K]^T + bias[N]. fp32 in/out (harness maps fp16
// reference -> fp32 buffers), bf16 MFMA compute (2% threshold).
//
// Round 14: the session's 50% plateau decomposed. (1) VGPR_Count excludes
// AGPR: r5's 256^2 kernel was 112+128=240 regs/lane -> hard 1 block/CU.
// (2) LDS arithmetic: 0.375-0.5 ds_read_b128 per MFMA puts LDS-read cycles
// >= MFMA cycles -> a single lockstep block serializes read<->MFMA; only a
// SECOND independent block per CU overlaps them (m114). (3) r6's FETCH 1 GB:
// 2.7-generation desync killed L3 locality. This round satisfies all:
//   * block 256Mx128N, 256 thr / 4 waves (2Mx2N), wave tile 128x64:
//     acc[8][4]=128 AGPR + ~100 VGPR ~= 230 < 256 -> 2 waves/SIMD ->
//     2 blocks/CU. reads/MFMA = 12/32 = 0.375 (r5's best ratio).
//   * ring-3 x 24 KB slots (A pair + W, one 32-k step) = 72 KB -> 144 KB
//     for 2 blocks. stage(j+2) during step j = 2 steps (~2200 cyc) cover;
//     steady-state wait vmcnt(6) (newest stage stays in flight).
//   * grid 1024 (2 generations); XCD-rect swizzle 16bm x 8bn: per-XCD W
//     working set 4 MB ~= L2, A pairs via L3 (64 MB < 256 MB).
//   * pack kernel: r5 verbatim (passed; 128x32 blocks, 2-bit XOR swizzle,
//     measured 0 LDS bank conflicts).
// Predicted: gemm 185-215 us @ 58-68% MfmaUtil, FETCH 300-450 MB; total
// ~440-460. Falsifier: ~240 us @ ~52% -> structure ceiling, revert to r0.

typedef unsigned short u16;
typedef unsigned int u32;
typedef __bf16 bf16x8 __attribute__((ext_vector_type(8)));
typedef float f32x4 __attribute__((ext_vector_type(4)));
typedef u32 u32x4 __attribute__((ext_vector_type(4)));

#define M_DIM 8192
#define N_DIM 4096
#define K_DIM 4096

#define NT 128                          // 32-k K-steps
#define BLK_ELEMS 4096                  // 128 rows x 32 k per packed block
#define SLOT_ELEMS 12288                // ring slot: A0 + A1 + W blocks

#define A_CHUNKS ((M_DIM / 128) * NT * 128 * 4)   // 4,194,304 16B chunks
#define W_CHUNKS ((N_DIM / 128) * NT * 128 * 4)   // 2,097,152
#define A_PACK_BYTES ((size_t)A_CHUNKS * 16)      // 64 MiB
#define W_PACK_BYTES ((size_t)W_CHUNKS * 16)      // 32 MiB

// pack two fp32 -> (bf16(hi)<<16)|bf16(lo) by byte-perm truncation
__device__ __forceinline__ u32 pack2bf(float lo, float hi) {
    return __builtin_amdgcn_perm(__float_as_uint(hi), __float_as_uint(lo),
                                 0x07060302u);
}

__device__ __forceinline__ void g2l16(const u16* g, __bf16* l) {
    __builtin_amdgcn_global_load_lds((__attribute__((address_space(1))) void*)g,
                                     (__attribute__((address_space(3))) void*)l,
                                     16, 0, 0);
}

// ---------------- Phase 1: convert + block-pack + swizzle (r5 verbatim) -----
// Packed layout: [panel][kstep][row][cp], 16B chunk cp at row r holds source
// chunk c = cp ^ ((r>>1)&3). One thread per chunk. A wave covers 16 rows x 4
// chunks: per row the 4 chunks are a permutation of one contiguous 128 B
// source segment (coalesced); writes fully linear (1 KiB/wave).
__global__ __launch_bounds__(256) void pack_bf16_kernel(
    const float* __restrict__ A, const float* __restrict__ W,
    u32x4* __restrict__ aP, u32x4* __restrict__ wP)
{
    int gid = blockIdx.x * 256 + threadIdx.x;
    const float* src;
    u32x4* dst;
    int id;
    if (gid < A_CHUNKS) { src = A; dst = aP; id = gid; }
    else                { src = W; dst = wP; id = gid - A_CHUNKS; }

    const int cp  = id & 3;
    const int row = (id >> 2) & 127;
    const int j   = (id >> 9) & 127;          // k-step
    const int mp  = id >> 16;                 // 128-row panel
    const int c   = cp ^ ((row >> 1) & 3);    // source chunk

    const float* p = src + (size_t)(mp * 128 + row) * K_DIM + j * 32 + c * 8;
    f32x4 v0 = __builtin_nontemporal_load((const f32x4*)(p));
    f32x4 v1 = __builtin_nontemporal_load((const f32x4*)(p + 4));
    dst[id] = u32x4{pack2bf(v0[0], v0[1]), pack2bf(v0[2], v0[3]),
                    pack2bf(v1[0], v1[1]), pack2bf(v1[2], v1[3])};
}

// ---------------- Phase 2: 256x128 ring-3 counted-vmcnt GEMM ---------------
// 256 thr / 4 waves (2M x 2N); wave tile 128x64 (acc[8][4]). Ring slot holds
// one 32-k K-step: A blocks {2bm, 2bm+1} + W block {bn}, 8 KB each. Steady
// state: stage(j+2) issued during step j (2 steps of cover); wait vmcnt(6)
// keeps the newest stage in flight. 6 g2l16 per thread per stage.
__global__ __launch_bounds__(256, 2) void gemm256x128_ring3_kernel(
    const u16* __restrict__ aP,      // packed A blocks (128x32, swizzled)
    const u16* __restrict__ wP,      // packed W blocks (128x32, swizzled)
    const float* __restrict__ bias,  // [N] fp32
    float* __restrict__ C)           // [M, N] fp32
{
    __shared__ __attribute__((aligned(16))) __bf16 ring[3][SLOT_ELEMS];

    const int tid  = threadIdx.x;
    const int lane = tid & 63;
    const int wave = tid >> 6;        // 0..3
    const int quad = lane >> 4;
    const int l16  = lane & 15;
    const int wm   = wave >> 1;       // 0..1 (128-row M half)
    const int wn   = wave & 1;        // 0..1 (64-col N half)

    // XCD-rect swizzle: 1024 blocks -> 8 rects of 16bm x 8bn. Per-XCD W
    // working set = 8 panels x 512 KB = 4 MB ~= L2; A pairs stream via L3.
    const int bid = blockIdx.x;
    const int x   = bid & 7;          // XCD (dispatch round-robin assumption)
    const int s   = bid >> 3;         // 0..127 within rect
    const int bm  = (x >> 2) * 16 + (s >> 3);   // 0..31 (256-row A pair)
    const int bn  = (x & 3) * 8 + (s & 7);      // 0..31 (128-row W panel)

    const u16* aB0 = aP + (size_t)(bm * 2    ) * NT * BLK_ELEMS;
    const u16* aB1 = aP + (size_t)(bm * 2 + 1) * NT * BLK_ELEMS;
    const u16* wB  = wP + (size_t)bn * NT * BLK_ELEMS;

    auto stage = [&](int t, int sl) {
        __bf16* sp = &ring[sl][0];
        const size_t o = (size_t)t * BLK_ELEMS + tid * 8;
        g2l16(aB0 + o,        sp + tid * 8);
        g2l16(aB0 + o + 2048, sp + 2048 + tid * 8);
        g2l16(aB1 + o,        sp + 4096 + tid * 8);
        g2l16(aB1 + o + 2048, sp + 6144 + tid * 8);
        g2l16(wB + o,         sp + 8192 + tid * 8);
        g2l16(wB + o + 2048,  sp + 10240 + tid * 8);
    };

    f32x4 acc[8][4];
#pragma unroll
    for (int i = 0; i < 8; ++i)
#pragma unroll
        for (int j = 0; j < 4; ++j)
            acc[i][j] = f32x4{0.f, 0.f, 0.f, 0.f};

    // read offsets (elems in slot). Rows touched = 16*k + l16, so the pack
    // swizzle bits (row>>1)&3 == (l16>>1)&3 -> constant per lane.
    const int cpq  = (quad ^ ((l16 >> 1) & 3)) * 8;
    const int aOff = wm * 4096 + l16 * 32 + cpq;          // + rb*512
    const int bOff = 8192 + (wn * 64 + l16) * 32 + cpq;   // + nb*512

    stage(0, 0);
    stage(1, 1);

    int sr = 0;       // slot of step j
    int sw = 2;       // slot of step j+2
    for (int j = 0; j < NT; ++j) {
        // counted wait: stages j and j+1 in flight (12 ops); keep newest 6.
        if (j + 1 < NT) asm volatile("s_waitcnt vmcnt(6)" ::: "memory");
        else            asm volatile("s_waitcnt vmcnt(0)" ::: "memory");
        __builtin_amdgcn_s_barrier();
        asm volatile("" ::: "memory");   // pin stage/ds_read after barrier

        if (j + 2 < NT) stage(j + 2, sw);   // overwrites slot of step j-1

        const __bf16* L = &ring[sr][0];
        bf16x8 af[8], bfr[4];
#pragma unroll
        for (int rb = 0; rb < 8; ++rb)
            af[rb] = *(const bf16x8*)&L[aOff + rb * 512];
#pragma unroll
        for (int nb = 0; nb < 4; ++nb)
            bfr[nb] = *(const bf16x8*)&L[bOff + nb * 512];

        __builtin_amdgcn_s_setprio(1);
#pragma unroll
        for (int rb = 0; rb < 8; ++rb)
#pragma unroll
            for (int nb = 0; nb < 4; ++nb)
                acc[rb][nb] = __builtin_amdgcn_mfma_f32_16x16x32_bf16(
                    af[rb], bfr[nb], acc[rb][nb], 0, 0, 0);
        __builtin_amdgcn_s_setprio(0);

        sr = (sr == 2) ? 0 : sr + 1;
        sw = (sw == 2) ? 0 : sw + 1;
    }

    // epilogue: C/D layout col = lane&15, row = quad*4 + reg; fp32 out + bias
    const int colBase = bn * 128 + wn * 64 + l16;
    const int rowBase = bm * 256 + wm * 128 + quad * 4;
#pragma unroll
    for (int nb = 0; nb < 4; ++nb) {
        const int col = colBase + nb * 16;
        const float bv = bias[col];
#pragma unroll
        for (int rb = 0; rb < 8; ++rb) {
            const int row = rowBase + rb * 16;
#pragma unroll
            for (int r = 0; r < 4; ++r)
                C[(size_t)(row + r) * N_DIM + col] = acc[rb][nb][r] + bv;
        }
    }
}

// ---------------- Fallback (round-3 kernel, ws too small) ----------------
__global__ __launch_bounds__(256, 2) void linear_f32_bf16mfma_kernel(
    const float* __restrict__ A, const float* __restrict__ W,
    const float* __restrict__ bias, float* __restrict__ C)
{
    __shared__ __attribute__((aligned(16))) __bf16 sA[128 * 64];
    __shared__ __attribute__((aligned(16))) __bf16 sB[128 * 64];

    const int tid  = threadIdx.x;
    const int lane = tid & 63;
    const int wave = tid >> 6;
    const int quad = lane >> 4;
    const int l16  = lane & 15;
    const int wm   = wave >> 1;
    const int wn   = wave & 1;
    const int bn = blockIdx.x;
    const int bm = blockIdx.y;
    const int srow = tid >> 3;
    const int scol = (tid & 7) * 8;

    const float* aBase = A + (size_t)(bm * 128 + srow) * K_DIM + scol;
    const float* bBase = W + (size_t)(bn * 128 + srow) * K_DIM + scol;

    f32x4 acc[4][4];
#pragma unroll
    for (int i = 0; i < 4; ++i)
#pragma unroll
        for (int j = 0; j < 4; ++j)
            acc[i][j] = f32x4{0.f, 0.f, 0.f, 0.f};

    const int aRow = wm * 64 + l16;
    const int bRow = wn * 64 + l16;
    const int kOff = quad * 8;

    for (int k0 = 0; k0 < K_DIM; k0 += 64) {
        f32x4 ga[4][2], gb[4][2];
#pragma unroll
        for (int it = 0; it < 4; ++it) {
            const float* pa = aBase + (size_t)(it * 32) * K_DIM + k0;
            const float* pb = bBase + (size_t)(it * 32) * K_DIM + k0;
            ga[it][0] = *(const f32x4*)(pa);
            ga[it][1] = *(const f32x4*)(pa + 4);
            gb[it][0] = *(const f32x4*)(pb);
            gb[it][1] = *(const f32x4*)(pb + 4);
        }
        u32x4 wa[4], wb[4];
#pragma unroll
        for (int it = 0; it < 4; ++it) {
            wa[it] = u32x4{pack2bf(ga[it][0][0], ga[it][0][1]),
                           pack2bf(ga[it][0][2], ga[it][0][3]),
                           pack2bf(ga[it][1][0], ga[it][1][1]),
                           pack2bf(ga[it][1][2], ga[it][1][3])};
            wb[it] = u32x4{pack2bf(gb[it][0][0], gb[it][0][1]),
                           pack2bf(gb[it][0][2], gb[it][0][3]),
                           pack2bf(gb[it][1][0], gb[it][1][1]),
                           pack2bf(gb[it][1][2], gb[it][1][3])};
        }
        __syncthreads();
#pragma unroll
        for (int it = 0; it < 4; ++it) {
            *(u32x4*)&sA[tid * 8 + it * 2048] = wa[it];
            *(u32x4*)&sB[tid * 8 + it * 2048] = wb[it];
        }
        __syncthreads();
#pragma unroll
        for (int ks = 0; ks < 64; ks += 32) {
            bf16x8 af[4], bfr[4];
#pragma unroll
            for (int mi = 0; mi < 4; ++mi)
                af[mi] = *(const bf16x8*)&sA[(aRow + mi * 16) * 64 + ks + kOff];
#pragma unroll
            for (int ni = 0; ni < 4; ++ni)
                bfr[ni] = *(const bf16x8*)&sB[(bRow + ni * 16) * 64 + ks + kOff];
#pragma unroll
            for (int mi = 0; mi < 4; ++mi)
#pragma unroll
                for (int ni = 0; ni < 4; ++ni)
                    acc[mi][ni] = __builtin_amdgcn_mfma_f32_16x16x32_bf16(
                        af[mi], bfr[ni], acc[mi][ni], 0, 0, 0);
        }
    }
    const int colBase = bn * 128 + wn * 64 + l16;
    const int rowBase = bm * 128 + wm * 64 + quad * 4;
#pragma unroll
    for (int ni = 0; ni < 4; ++ni) {
        const int col = colBase + ni * 16;
        const float bv = bias[col];
#pragma unroll
        for (int mi = 0; mi < 4; ++mi) {
            const int row = rowBase + mi * 16;
#pragma unroll
            for (int r = 0; r < 4; ++r)
                C[(size_t)(row + r) * N_DIM + col] = acc[mi][ni][r] + bv;
        }
    }
}

extern "C" void kernel_launch(void* const* d_in, const int* in_sizes, int n_in,
                              void* d_out, int out_size, void* d_ws, size_t ws_size,
                              hipStream_t stream) {
    const float* x = (const float*)d_in[0];   // [8192, 4096]
    const float* w = (const float*)d_in[1];   // [4096, 4096]
    const float* b = (const float*)d_in[2];   // [4096]
    float* out = (float*)d_out;

    if (ws_size >= A_PACK_BYTES + W_PACK_BYTES) {
        u32x4* aP = (u32x4*)d_ws;
        u32x4* wP = (u32x4*)((char*)d_ws + A_PACK_BYTES);
        const int total_chunks = A_CHUNKS + W_CHUNKS;
        pack_bf16_kernel<<<total_chunks / 256, 256, 0, stream>>>(x, w, aP, wP);
        gemm256x128_ring3_kernel<<<dim3(1024), 256, 0, stream>>>(
            (const u16*)aP, (const u16*)wP, b, out);
    } else {
        dim3 grid(N_DIM / 128, M_DIM / 128);
        linear_f32_bf16mfma_kernel<<<grid, 256, 0, stream>>>(x, w, b, out);
    }
}